// Round 2
// baseline (103.006 us; speedup 1.0000x reference)
//
#include <hip/hip_runtime.h>
#include <math.h>

// Problem constants
#define B_N   2048
#define D_IN_ 16
#define Q_N   512
#define H_N   128

#define QCHUNK 64
#define NQC    (Q_N / QCHUNK)          // 8
#define NB     8
#define RPB    16                      // rows per block
#define NRB    (B_N / RPB)             // 128

typedef float v2f __attribute__((ext_vector_type(2)));

static constexpr float kC = 2.88539008177792681472f;  // 2 * log2(e)

// ---------------------------------------------------------------------------
// Fully fused:
//   out[b] = sum_h W2[h]*T[b,h] + b2*S,  T = sum_q y_q * tanh(u_{q,h}+v_{b,h})
// Using tanh(x) = 1 - 2/(1 + e^{2x}) and e^{2(u+v)} = E_q * F_b with
// E = exp2(kC*u), F = exp2(kC*v), kC = 2*log2(e):
//   per-chunk contribution to out[b] =
//     sum_h W2[h] * sum_{q in c} (-2 y_q) / (1 + E*F)   [acc, inner loop]
//   + Sc * (sum_h W2[h] + b2)                           [analytic constant]
// Inner loop per element: pk_mul, pk_add, v_rcp_f32, pk_fma — no exp.
// grid = 128 row-blocks x 8 q-chunks, block = 256 (128 h x 2 row-groups),
// each thread owns NB=8 b-rows (F in regs) over a 64-q E tile in LDS.
// ---------------------------------------------------------------------------
__global__ __launch_bounds__(256) void fused_kernel(
    const float* __restrict__ input,
    const float* __restrict__ eq,
    const float* __restrict__ qx,
    const float* __restrict__ W1,
    const float* __restrict__ b1,
    const float* __restrict__ W2,
    const float* __restrict__ b2,
    float* __restrict__ out)
{
    __shared__ float E_s[QCHUNK * H_N];              // 32 KB: exp2(kC*u)
    __shared__ __align__(8) float y2_s[QCHUNK];      // -2*y_q
    __shared__ float in_s[RPB * D_IN_];              // 16 input rows (256 f)
    __shared__ float part[4][NB];
    __shared__ float w2p[2];
    __shared__ float Sc_s;

    const int t    = threadIdx.x;
    const int rb   = blockIdx.x & (NRB - 1);         // row-block [0,128)
    const int qc   = blockIdx.x >> 7;                // q-chunk   [0,8)
    const int h    = t & 127;
    const int bg   = t >> 7;                         // row group 0/1
    const int lane = t & 63;
    const int w    = t >> 6;
    const int q0   = qc * QCHUNK;                    // global q base

    // ---- stage input rows (RPB*D_IN_ == 256 == blockDim) ----
    in_s[t] = input[rb * RPB * D_IN_ + t];

    // ---- E tile: E[q][h] = exp2(kC*(qx0*W1[0,h]+qx1*W1[1,h]+b1[h])) ----
    {
        const float w1a = W1[h];
        const float w1b = W1[H_N + h];
        const float bh  = b1[h];
        #pragma unroll
        for (int i = 0; i < QCHUNK / 2; ++i) {       // 32 q's per thread
            const int ql = bg + 2 * i;
            const float x0 = qx[2 * (q0 + ql)];
            const float x1 = qx[2 * (q0 + ql) + 1];
            float s = fmaf(x1, w1b, fmaf(x0, w1a, bh));
            E_s[ql * H_N + h] = __builtin_amdgcn_exp2f(s * kC);
        }
    }

    // ---- y2 (= -2 sin(qx.eq)) + chunk sum Sc: wave 0 only ----
    if (w == 0) {
        const float e0 = eq[0], e1 = eq[1];
        const int qg = q0 + lane;
        const float a  = fmaf(qx[2 * qg + 1], e1, qx[2 * qg] * e0);
        const float yv = sinf(a);
        y2_s[lane] = -2.0f * yv;
        float s = yv;
        #pragma unroll
        for (int off = 32; off >= 1; off >>= 1)
            s += __shfl_down(s, off, 64);
        if (lane == 0) Sc_s = s;
    }
    // ---- W2 half-sums: waves 0 and 1 (h = lane, 64+lane) ----
    if (w < 2) {
        float s = W2[h];
        #pragma unroll
        for (int off = 32; off >= 1; off >>= 1)
            s += __shfl_down(s, off, 64);
        if (lane == 0) w2p[w] = s;
    }
    __syncthreads();

    // ---- F[r] = exp2(kC * v[b,h]),  v = input[b,:] . W1[2:,h] ----
    const int rowBase = bg * NB;                     // local row within block
    float F[NB];
    {
        float w1c[D_IN_];
        #pragma unroll
        for (int d = 0; d < D_IN_; ++d)
            w1c[d] = W1[(2 + d) * H_N + h];
        #pragma unroll
        for (int r = 0; r < NB; ++r) {
            float s = 0.0f;
            #pragma unroll
            for (int d = 0; d < D_IN_; ++d)
                s = fmaf(in_s[(rowBase + r) * D_IN_ + d], w1c[d], s);
            F[r] = __builtin_amdgcn_exp2f(s * kC);
        }
    }

    // ---- inner loop: acc_r = sum_q (-2 y_q) * rcp(1 + E_q*F_r) ----
    v2f F2[NB / 2], acc2[NB / 2];
    #pragma unroll
    for (int j = 0; j < NB / 2; ++j) {
        F2[j].x = F[2 * j]; F2[j].y = F[2 * j + 1];
        acc2[j].x = 0.0f;   acc2[j].y = 0.0f;
    }
    const v2f one = {1.0f, 1.0f};

    for (int q = 0; q < QCHUNK; q += 2) {
        const float e0 = E_s[q * H_N + h];           // 2 lanes/bank: free
        const float e1 = E_s[(q + 1) * H_N + h];
        const v2f y2q = *(const v2f*)&y2_s[q];       // broadcast pair
        const v2f ys0 = {y2q.x, y2q.x};
        const v2f ys1 = {y2q.y, y2q.y};
        #pragma unroll
        for (int j = 0; j < NB / 2; ++j) {
            v2f m0 = F2[j] * e0;
            v2f m1 = F2[j] * e1;
            v2f d0 = m0 + one;
            v2f d1 = m1 + one;
            v2f r0 = {__builtin_amdgcn_rcpf(d0.x), __builtin_amdgcn_rcpf(d0.y)};
            v2f r1 = {__builtin_amdgcn_rcpf(d1.x), __builtin_amdgcn_rcpf(d1.y)};
            acc2[j] = __builtin_elementwise_fma(ys0, r0, acc2[j]);
            acc2[j] = __builtin_elementwise_fma(ys1, r1, acc2[j]);
        }
    }

    // ---- epilogue: scale by W2[h], reduce over h, add analytic const ----
    const float w2 = W2[h];
    #pragma unroll
    for (int j = 0; j < NB / 2; ++j) {
        #pragma unroll
        for (int k = 0; k < 2; ++k) {
            float p = (k ? acc2[j].y : acc2[j].x) * w2;
            #pragma unroll
            for (int off = 32; off >= 1; off >>= 1)
                p += __shfl_down(p, off, 64);
            if (lane == 0) part[w][2 * j + k] = p;
        }
    }
    __syncthreads();

    if (t < 16) {
        const int r = t & 7, g = t >> 3;             // g: row group
        const float c0 = Sc_s * (w2p[0] + w2p[1] + b2[0]);
        const float s = part[2 * g][r] + part[2 * g + 1][r] + c0;
        atomicAdd(out + rb * RPB + g * NB + r, s);
    }
}

// ---------------------------------------------------------------------------
extern "C" void kernel_launch(void* const* d_in, const int* in_sizes, int n_in,
                              void* d_out, int out_size, void* d_ws, size_t ws_size,
                              hipStream_t stream)
{
    (void)in_sizes; (void)n_in; (void)d_ws; (void)ws_size;
    const float* input = (const float*)d_in[0];
    const float* eq    = (const float*)d_in[1];
    const float* qx    = (const float*)d_in[2];
    const float* W1    = (const float*)d_in[3];
    const float* b1    = (const float*)d_in[4];
    const float* W2    = (const float*)d_in[5];
    const float* b2    = (const float*)d_in[6];
    float* out = (float*)d_out;

    hipMemsetAsync(d_out, 0, (size_t)out_size * sizeof(float), stream);
    fused_kernel<<<dim3(NRB * NQC), dim3(256), 0, stream>>>(
        input, eq, qx, W1, b1, W2, b2, out);
}

// Round 3
// 83.759 us; speedup vs baseline: 1.2298x; 1.2298x over previous
//
#include <hip/hip_runtime.h>
#include <math.h>

// Problem constants
#define B_N   2048
#define D_IN_ 16
#define Q_N   512
#define H_N   128

#define QCHUNK 32                      // q's per main-kernel chunk
#define NQC    (Q_N / QCHUNK)          // 16
#define QPC    (QCHUNK / 4)            // 8 quads per chunk
#define NB     8                       // rows per thread
#define RPB    16                      // rows per block
#define NRB    (B_N / RPB)             // 128

// Workspace layout (float offsets)
//   coeff table: [quad 0..127][coef 0..7][h 0..127]; coef 0-3 = n0..n3 (num,
//   -2y folded), coef 4-7 = c1..c4 (den, c0=1 implicit). 131072 floats.
#define COEF_OFF 0
#define K0_OFF   131072                // K0 = S*(sum W2 + b2)
#define F_OFF    131136                // F[b][h] = exp2(kC * v[b,h]), 262144 f

static constexpr float kC = 2.88539008177792681472f;  // 2 * log2(e)

// ---------------------------------------------------------------------------
// Precompute:
//  blocks 0..1023   : F[b,h] = exp2(kC * input[b,:].W1[2:,h])
//  blocks 1024..1087: per-(quad,h) rational coeffs for
//                     sum_{i in quad} -2 y_i/(1+E_i F) = N(F)/P(F)
//  block 1088       : K0 = S*(sum W2 + b2), S = sum_q sin(qx_q . eq)
// ---------------------------------------------------------------------------
__global__ __launch_bounds__(256) void precompute_kernel(
    const float* __restrict__ input,
    const float* __restrict__ eq,
    const float* __restrict__ qx,
    const float* __restrict__ W1,
    const float* __restrict__ b1,
    const float* __restrict__ W2,
    const float* __restrict__ b2,
    float* __restrict__ ws)
{
    const int blk = blockIdx.x;
    const int t   = threadIdx.x;

    if (blk < 1024) {
        const int idx = blk * 256 + t;            // [0, 262144)
        const int row = idx >> 7, h = idx & 127;
        const float* inr = input + row * D_IN_;
        float s = 0.0f;
        #pragma unroll
        for (int d = 0; d < D_IN_; ++d)
            s = fmaf(inr[d], W1[(2 + d) * H_N + h], s);
        ws[F_OFF + idx] = __builtin_amdgcn_exp2f(s * kC);
    } else if (blk < 1088) {
        const int set  = (blk - 1024) * 256 + t;  // [0, 16384)
        const int quad = set >> 7, h = set & 127;
        const float w1a = W1[h], w1b = W1[H_N + h], bh = b1[h];
        const float e0 = eq[0], e1 = eq[1];
        // build N (deg 3) and P (deg 4, p0=1) incrementally
        float n0 = 0, n1 = 0, n2 = 0, n3 = 0;
        float p1 = 0, p2 = 0, p3 = 0, p4 = 0;
        #pragma unroll
        for (int i = 0; i < 4; ++i) {
            const int q = quad * 4 + i;
            const float x0 = qx[2 * q], x1 = qx[2 * q + 1];
            const float u = fmaf(x1, w1b, fmaf(x0, w1a, bh));
            const float E = __builtin_amdgcn_exp2f(u * kC);
            const float y = -2.0f * sinf(fmaf(x1, e1, x0 * e0));
            // N' = N*(1+Ex) + y*P ; P' = P*(1+Ex)  (descending, old values)
            n3 = fmaf(E, n2, fmaf(y, p3, n3));
            n2 = fmaf(E, n1, fmaf(y, p2, n2));
            n1 = fmaf(E, n0, fmaf(y, p1, n1));
            n0 = n0 + y;                           // p0 == 1
            p4 = fmaf(E, p3, p4);
            p3 = fmaf(E, p2, p3);
            p2 = fmaf(E, p1, p2);
            p1 = p1 + E;
        }
        float* dst = ws + COEF_OFF + quad * (8 * H_N) + h;
        dst[0 * H_N] = n0; dst[1 * H_N] = n1; dst[2 * H_N] = n2; dst[3 * H_N] = n3;
        dst[4 * H_N] = p1; dst[5 * H_N] = p2; dst[6 * H_N] = p3; dst[7 * H_N] = p4;
    } else {
        __shared__ float red[8];
        const float e0 = eq[0], e1 = eq[1];
        const int lane = t & 63, w = t >> 6;
        float s = 0.0f;
        #pragma unroll
        for (int i = 0; i < 2; ++i) {
            const int q = t + 256 * i;
            s += sinf(fmaf(qx[2 * q + 1], e1, qx[2 * q] * e0));
        }
        #pragma unroll
        for (int off = 32; off >= 1; off >>= 1)
            s += __shfl_down(s, off, 64);
        if (lane == 0) red[w] = s;
        float ws2 = (t < H_N) ? W2[t] : 0.0f;
        if (w < 2) {
            #pragma unroll
            for (int off = 32; off >= 1; off >>= 1)
                ws2 += __shfl_down(ws2, off, 64);
            if (lane == 0) red[4 + w] = ws2;
        }
        __syncthreads();
        if (t == 0) {
            const float S = red[0] + red[1] + red[2] + red[3];
            ws[K0_OFF] = S * (red[4] + red[5] + b2[0]);
        }
    }
}

// ---------------------------------------------------------------------------
// Main: out[b] = K0 + sum_h W2[h] * sum_quads N_{quad,h}(F_{b,h}) / P_{quad,h}(F_{b,h})
// grid = 128 row-blocks x 16 q-chunks, block = 256 (128 h x 2 row-groups),
// each thread: 8 rows (F in regs) x 8 quads (coeffs from 32KB LDS tile).
// Inner: 8 fma + 1 rcp per 4 elements.
// ---------------------------------------------------------------------------
__global__ __launch_bounds__(256, 4) void main_kernel(
    const float* __restrict__ ws,
    const float* __restrict__ W2,
    float* __restrict__ out)
{
    __shared__ float c_s[QPC * 8 * H_N];             // 32 KB coeff tile
    __shared__ float part[4][NB];

    const int t    = threadIdx.x;
    const int rb   = blockIdx.x & (NRB - 1);         // row-block [0,128)
    const int qc   = blockIdx.x >> 7;                // q-chunk   [0,16)
    const int h    = t & 127;
    const int bg   = t >> 7;                         // row group 0/1
    const int lane = t & 63;
    const int w    = t >> 6;

    // ---- stage coeff tile (8 quads x 8 coefs x 128 h = 8192 floats) ----
    {
        const float4* src = (const float4*)(ws + COEF_OFF + qc * (QPC * 8 * H_N));
        float4* dst = (float4*)c_s;
        #pragma unroll
        for (int i = 0; i < (QPC * 8 * H_N / 4) / 256; ++i)   // 8 iters
            dst[t + 256 * i] = src[t + 256 * i];
    }

    // ---- load F for my 8 rows (precomputed, coalesced across h) ----
    const int rowBase = rb * RPB + bg * NB;
    float F[NB], acc[NB];
    #pragma unroll
    for (int r = 0; r < NB; ++r) {
        F[r] = ws[F_OFF + (rowBase + r) * H_N + h];
        acc[r] = 0.0f;
    }
    __syncthreads();

    // ---- inner: per quad, Horner num(deg3)/den(deg4), 8 rows ----
    #pragma unroll
    for (int qd = 0; qd < QPC; ++qd) {
        const float* cp = c_s + qd * (8 * H_N) + h;
        const float n0 = cp[0 * H_N], n1 = cp[1 * H_N];
        const float n2 = cp[2 * H_N], n3 = cp[3 * H_N];
        const float c1 = cp[4 * H_N], c2 = cp[5 * H_N];
        const float c3 = cp[6 * H_N], c4 = cp[7 * H_N];
        #pragma unroll
        for (int r = 0; r < NB; ++r) {
            const float Fr  = F[r];
            const float den = fmaf(fmaf(fmaf(fmaf(c4, Fr, c3), Fr, c2), Fr, c1), Fr, 1.0f);
            const float num = fmaf(fmaf(fmaf(n3, Fr, n2), Fr, n1), Fr, n0);
            acc[r] = fmaf(num, __builtin_amdgcn_rcpf(den), acc[r]);
        }
    }

    // ---- epilogue: x W2[h], reduce over h, add K0 once (qc==0) ----
    const float w2 = W2[h];
    #pragma unroll
    for (int r = 0; r < NB; ++r) {
        float p = acc[r] * w2;
        #pragma unroll
        for (int off = 32; off >= 1; off >>= 1)
            p += __shfl_down(p, off, 64);
        if (lane == 0) part[w][r] = p;
    }
    __syncthreads();

    if (t < 16) {
        const int r = t & 7, g = t >> 3;
        float s = part[2 * g][r] + part[2 * g + 1][r];
        if (qc == 0) s += ws[K0_OFF];
        atomicAdd(out + rb * RPB + g * NB + r, s);
    }
}

// ---------------------------------------------------------------------------
extern "C" void kernel_launch(void* const* d_in, const int* in_sizes, int n_in,
                              void* d_out, int out_size, void* d_ws, size_t ws_size,
                              hipStream_t stream)
{
    (void)in_sizes; (void)n_in; (void)ws_size;
    const float* input = (const float*)d_in[0];
    const float* eq    = (const float*)d_in[1];
    const float* qx    = (const float*)d_in[2];
    const float* W1    = (const float*)d_in[3];
    const float* b1    = (const float*)d_in[4];
    const float* W2    = (const float*)d_in[5];
    const float* b2    = (const float*)d_in[6];
    float* out = (float*)d_out;
    float* ws  = (float*)d_ws;

    hipMemsetAsync(d_out, 0, (size_t)out_size * sizeof(float), stream);
    precompute_kernel<<<dim3(1089), dim3(256), 0, stream>>>(
        input, eq, qx, W1, b1, W2, b2, ws);
    main_kernel<<<dim3(NRB * NQC), dim3(256), 0, stream>>>(ws, W2, out);
}

// Round 5
// 82.703 us; speedup vs baseline: 1.2455x; 1.0128x over previous
//
#include <hip/hip_runtime.h>
#include <math.h>

// Problem constants
#define B_N   2048
#define D_IN_ 16
#define Q_N   512
#define H_N   128

#define QCHUNK 32                      // q's per block
#define NQC    (Q_N / QCHUNK)          // 16
#define QPC    (QCHUNK / 4)            // 8 quads per chunk
#define NB     8                       // rows per thread
#define RPB    16                      // rows per block
#define NRB    (B_N / RPB)             // 128

static constexpr float kC = 2.88539008177792681472f;  // 2 * log2(e)

// ---------------------------------------------------------------------------
// Single fused kernel (round-3 verified math, fused; NO inline asm).
//   out[b] = sum_chunks [ Sc*(sumW2+b2) + sum_h W2[h] * sum_quads N(F)/P(F) ]
// Per quad (4 q's): sum_i -2 y_i/(1+E_i F) = N(F)/P(F); N deg3 (y folded),
// P deg4 (p0=1); E = exp2(kC*u_qh), F = exp2(kC*v_bh), kC = 2*log2(e).
// Inner: 8 fma + 1 rcp per 4 elements.
// grid = 128 row-blocks x 16 q-chunks, block = 256 (128 h x 2 row-groups);
// each thread: 8 rows (F in regs) x 8 quads (coeffs from 32 KB LDS tile,
// [quad][coef][h] layout -> stride-1 in h, 2 lanes/bank = conflict-free).
// ---------------------------------------------------------------------------
__global__ __launch_bounds__(256, 4) void fused_kernel(
    const float* __restrict__ input,
    const float* __restrict__ eq,
    const float* __restrict__ qx,
    const float* __restrict__ W1,
    const float* __restrict__ b1,
    const float* __restrict__ W2,
    const float* __restrict__ b2,
    float* __restrict__ out)
{
    __shared__ float c_s[QPC * 8 * H_N];     // 32 KB: [quad][coef][h]
    __shared__ float in_s[RPB * D_IN_];      // 256 floats
    __shared__ float qx_s[QCHUNK * 2];       // 64 floats
    __shared__ float y_s[QCHUNK];            // -2*sin(qx.eq)
    __shared__ float part[4][NB];
    __shared__ float Sc_s, w2sum_s;

    const int t    = threadIdx.x;
    const int rb   = blockIdx.x & (NRB - 1); // row-block [0,128)
    const int qc   = blockIdx.x >> 7;        // q-chunk   [0,16)
    const int h    = t & 127;
    const int bg   = t >> 7;                 // row group 0/1
    const int lane = t & 63;
    const int w    = t >> 6;

    // ---- phase 0: stage input rows + qx chunk; y + Sc (wave 0); sum W2 ----
    in_s[t] = input[rb * (RPB * D_IN_) + t];
    if (t < QCHUNK * 2) qx_s[t] = qx[qc * (QCHUNK * 2) + t];
    if (w == 0) {
        float s = 0.0f;
        if (lane < QCHUNK) {
            const int q = qc * QCHUNK + lane;
            const float a  = fmaf(qx[2 * q + 1], eq[1], qx[2 * q] * eq[0]);
            const float yv = sinf(a);
            y_s[lane] = -2.0f * yv;
            s = yv;
        }
        #pragma unroll
        for (int off = 32; off >= 1; off >>= 1)   // full-wave reduction
            s += __shfl_down(s, off, 64);
        if (lane == 0) Sc_s = s;
    }
    if (w == 1) {                            // sum W2 over 128 h
        float s = W2[lane] + W2[64 + lane];
        #pragma unroll
        for (int off = 32; off >= 1; off >>= 1)
            s += __shfl_down(s, off, 64);
        if (lane == 0) w2sum_s = s;
    }
    const float w2 = W2[h];
    __syncthreads();

    // ---- phase 1: coef tile. thread (h,bg) builds quads bg*4+{0..3} ----
    {
        const float w1a = W1[h], w1b = W1[H_N + h], bh = b1[h];
        #pragma unroll
        for (int k = 0; k < 4; ++k) {
            const int qd = bg * 4 + k;       // quad index [0,8)
            float n0 = 0, n1 = 0, n2 = 0, n3 = 0;
            float p1 = 0, p2 = 0, p3 = 0, p4 = 0;
            #pragma unroll
            for (int i = 0; i < 4; ++i) {
                const int ql = qd * 4 + i;   // local q [0,32)
                const float x0 = qx_s[2 * ql], x1 = qx_s[2 * ql + 1];
                const float u = fmaf(x1, w1b, fmaf(x0, w1a, bh));
                const float E = __builtin_amdgcn_exp2f(u * kC);
                const float y = y_s[ql];     // already -2*sin
                // N' = N*(1+Ex) + y*P ; P' = P*(1+Ex)  (descending order)
                n3 = fmaf(E, n2, fmaf(y, p3, n3));
                n2 = fmaf(E, n1, fmaf(y, p2, n2));
                n1 = fmaf(E, n0, fmaf(y, p1, n1));
                n0 = n0 + y;                 // p0 == 1
                p4 = fmaf(E, p3, p4);
                p3 = fmaf(E, p2, p3);
                p2 = fmaf(E, p1, p2);
                p1 = p1 + E;
            }
            float* dst = c_s + qd * (8 * H_N) + h;
            dst[0 * H_N] = n0; dst[1 * H_N] = n1;
            dst[2 * H_N] = n2; dst[3 * H_N] = n3;
            dst[4 * H_N] = p1; dst[5 * H_N] = p2;
            dst[6 * H_N] = p3; dst[7 * H_N] = p4;
        }
    }

    // ---- phase 2: F for my 8 rows (in_s is pre-barrier data) ----
    float F[NB], acc[NB];
    {
        float w1c[D_IN_];
        #pragma unroll
        for (int d = 0; d < D_IN_; ++d)
            w1c[d] = W1[(2 + d) * H_N + h];
        const float4* in4 = (const float4*)in_s;
        #pragma unroll
        for (int r = 0; r < NB; ++r) {
            const int row = bg * NB + r;
            float s = 0.0f;
            #pragma unroll
            for (int k = 0; k < 4; ++k) {
                const float4 a = in4[row * 4 + k];
                s = fmaf(a.x, w1c[4 * k + 0], s);
                s = fmaf(a.y, w1c[4 * k + 1], s);
                s = fmaf(a.z, w1c[4 * k + 2], s);
                s = fmaf(a.w, w1c[4 * k + 3], s);
            }
            F[r] = __builtin_amdgcn_exp2f(s * kC);
            acc[r] = 0.0f;
        }
    }
    __syncthreads();

    // ---- phase 3: rational inner loop (8 fma + 1 rcp per 4 elements) ----
    #pragma unroll
    for (int qd = 0; qd < QPC; ++qd) {
        const float* cp = c_s + qd * (8 * H_N) + h;
        const float n0 = cp[0 * H_N], n1 = cp[1 * H_N];
        const float n2 = cp[2 * H_N], n3 = cp[3 * H_N];
        const float c1 = cp[4 * H_N], c2 = cp[5 * H_N];
        const float c3 = cp[6 * H_N], c4 = cp[7 * H_N];
        #pragma unroll
        for (int r = 0; r < NB; ++r) {
            const float Fr  = F[r];
            const float den = fmaf(fmaf(fmaf(fmaf(c4, Fr, c3), Fr, c2), Fr, c1), Fr, 1.0f);
            const float num = fmaf(fmaf(fmaf(n3, Fr, n2), Fr, n1), Fr, n0);
            acc[r] = fmaf(num, __builtin_amdgcn_rcpf(den), acc[r]);
        }
    }

    // ---- epilogue: x W2[h], reduce over h, add per-chunk constant ----
    #pragma unroll
    for (int r = 0; r < NB; ++r) {
        float p = acc[r] * w2;
        #pragma unroll
        for (int off = 32; off >= 1; off >>= 1)
            p += __shfl_down(p, off, 64);
        if (lane == 0) part[w][r] = p;
    }
    __syncthreads();

    if (t < 16) {
        const int r = t & 7, g = t >> 3;
        const float k0c = Sc_s * (w2sum_s + b2[0]);   // this chunk's constant
        const float s = part[2 * g][r] + part[2 * g + 1][r] + k0c;
        atomicAdd(out + rb * RPB + g * NB + r, s);
    }
}

// ---------------------------------------------------------------------------
extern "C" void kernel_launch(void* const* d_in, const int* in_sizes, int n_in,
                              void* d_out, int out_size, void* d_ws, size_t ws_size,
                              hipStream_t stream)
{
    (void)in_sizes; (void)n_in; (void)d_ws; (void)ws_size;
    const float* input = (const float*)d_in[0];
    const float* eq    = (const float*)d_in[1];
    const float* qx    = (const float*)d_in[2];
    const float* W1    = (const float*)d_in[3];
    const float* b1    = (const float*)d_in[4];
    const float* W2    = (const float*)d_in[5];
    const float* b2    = (const float*)d_in[6];
    float* out = (float*)d_out;

    hipMemsetAsync(d_out, 0, (size_t)out_size * sizeof(float), stream);
    fused_kernel<<<dim3(NRB * NQC), dim3(256), 0, stream>>>(
        input, eq, qx, W1, b1, W2, b2, out);
}